// Round 6
// baseline (555.761 us; speedup 1.0000x reference)
//
#include <hip/hip_runtime.h>
#include <cstdint>

#define NQ 196
#define DIMX 384
#define QKVD 2304
#define VAD 1536
#define NHD 12
#define MTOT 25088  // 128*196

#define KSTR 40    // u16 stride of K tile in attn LDS
#define VSTR 232   // u16 stride of V^T rows in attn LDS
#define VTS 224    // u16 stride of Vt rows in global (padded, zero tail)
#define BTS 208    // f32 stride of expanded bias table
#define TSTR 140   // u16 stride of gemm0 epilogue LDS tile

typedef unsigned int u32;
typedef unsigned short u16;
typedef __bf16 bf16_t;
typedef bf16_t bf16x8 __attribute__((ext_vector_type(8)));
typedef float f32x4 __attribute__((ext_vector_type(4)));

__device__ inline u16 f2b(float f) {
  u32 u = __float_as_uint(f);
  u32 r = (u + 0x7fffu + ((u >> 16) & 1u)) >> 16;
  return (u16)r;
}
__device__ inline float b2f(u16 u) { return __uint_as_float(((u32)u) << 16); }
__device__ inline int iabs(int v) { return v < 0 ? -v : v; }

__device__ inline void gld_lds16(const void* g, void* l) {
  __builtin_amdgcn_global_load_lds((__attribute__((address_space(1))) void*)g,
                                   (__attribute__((address_space(3))) void*)l,
                                   16, 0, 0);
}

// ---------------- conversion / BN-table helpers ----------------

__global__ void cvt_kernel(const float* __restrict__ in, u16* __restrict__ out, int n4) {
  int i = blockIdx.x * 256 + threadIdx.x;
  if (i >= n4) return;
  float4 v = ((const float4*)in)[i];
  ushort4 o;
  o.x = f2b(v.x); o.y = f2b(v.y); o.z = f2b(v.z); o.w = f2b(v.w);
  ((ushort4*)out)[i] = o;
}

// QKV weight: bf16 + row reorder so new cols = [Q 12*32 | K 12*32 | V 12*128]
__global__ void cvt_wqkv(const float* __restrict__ in, u16* __restrict__ out) {
  int i = blockIdx.x * 256 + threadIdx.x;
  if (i >= QKVD * DIMX / 4) return;
  const int newc = i / (DIMX / 4);
  const int kc = (i - newc * (DIMX / 4)) * 4;
  int oldc;
  if (newc < 384)      { int h = newc >> 5;              oldc = h * 192 + (newc & 31); }
  else if (newc < 768) { int t = newc - 384; int h = t >> 5; oldc = h * 192 + 32 + (t & 31); }
  else                 { int t = newc - 768; int h = t >> 7; oldc = h * 192 + 64 + (t & 127); }
  float4 v = *(const float4*)(in + (size_t)oldc * DIMX + kc);
  ushort4 o;
  o.x = f2b(v.x); o.y = f2b(v.y); o.z = f2b(v.z); o.w = f2b(v.w);
  *(ushort4*)(out + (size_t)newc * DIMX + kc) = o;
}

__global__ void bn_tab(const float* __restrict__ g, const float* __restrict__ be,
                       const float* __restrict__ mn, const float* __restrict__ vr,
                       float* __restrict__ inv, float* __restrict__ off, int n) {
  int i = blockIdx.x * 256 + threadIdx.x;
  if (i >= n) return;
  float iv = g[i] * rsqrtf(vr[i] + 1e-5f);
  inv[i] = iv;
  off[i] = be[i] - mn[i] * iv;
}

// BN table for QKV, written in the reordered column order
__global__ void bn_tab_qkv(const float* __restrict__ g, const float* __restrict__ be,
                           const float* __restrict__ mn, const float* __restrict__ vr,
                           float* __restrict__ inv, float* __restrict__ off) {
  int i = blockIdx.x * 256 + threadIdx.x;  // old column index
  if (i >= QKVD) return;
  const int h = i / 192, r = i - h * 192;
  const int newc = (r < 32) ? h * 32 + r
                 : (r < 64) ? 384 + h * 32 + (r - 32)
                            : 768 + h * 128 + (r - 64);
  float iv = g[i] * rsqrtf(vr[i] + 1e-5f);
  inv[newc] = iv;
  off[newc] = be[i] - mn[i] * iv;
}

// Expanded bias table: biasT[h][m][n] = biases[h, |yn-ym|*14 + |xn-xm|],
// padded to 208x208 with -1e30 so it doubles as the validity mask.
__global__ void bias_expand(const float* __restrict__ biases, float* __restrict__ bt) {
  int i = blockIdx.x * 256 + threadIdx.x;
  if (i >= NHD * BTS * BTS) return;
  const int h = i / (BTS * BTS), r = i - h * BTS * BTS;
  const int m = r / BTS, n = r - m * BTS;
  float v = -1e30f;
  if (m < NQ && n < NQ) {
    const int ym = m / 14, xm = m - ym * 14;
    const int yn = n / 14, xn = n - yn * 14;
    v = biases[h * NQ + iabs(yn - ym) * 14 + iabs(xn - xm)];
  }
  bt[i] = v;
}

// Zero-fill the padded tail columns n in [196,224) of Vt so PV MFMA pads are NaN-free.
// (Zero chunks map onto all permuted pad slots; real chunk 192..195 is a fixed point.)
__global__ void pad_vt(u16* __restrict__ Vt) {
  int i = blockIdx.x * 256 + threadIdx.x;
  if (i >= 128 * NHD * 128 * 14) return;
  const int row = i / 14, c = i - row * 14;
  *(u32*)(Vt + (size_t)row * VTS + NQ + c * 2) = 0u;
}

// ---------------- bf16 MFMA GEMM, C = A * B^T (both K-contiguous) ----------------
// MODE 0: QKV (reordered cols). Epilogue: BN fold -> LDS tile -> vector stores.
//   blocks 0-2: Q (4 heads each), 3-5: K, 6-17: V (1 head each, stored transposed
//   (b,h,d,n) stride VTS, with n-columns PERMUTED within each 32-block so attn's
//   lane-local P fragments line up: slot 8*fj+j <-> true-n 32kc+16*(j>>2)+4*fj+(j&3)).
// MODE 1: proj epilogue (BN fold, fp32 out)

template <int MODE>
__global__ __launch_bounds__(256) void gemm_bt(
    const u16* __restrict__ A, const u16* __restrict__ B, int K,
    const float* __restrict__ inv, const float* __restrict__ off,
    u16* __restrict__ Qb, u16* __restrict__ Kb, u16* __restrict__ Vt,
    float* __restrict__ out) {
  constexpr int LDSU = (MODE == 0) ? 128 * TSTR : 8192;  // epilogue tile unions As/Bs
  __shared__ __align__(16) u16 lds[LDSU];
  u16* As = lds;
  u16* Bs = lds + 4096;
  const int tid = threadIdx.x;
  const int wid = tid >> 6, lane = tid & 63;
  const int wm = wid & 1, wn = wid >> 1;
  const int fr = lane & 15, fk = (lane >> 4) << 3;
  const u16* Ab = A + (size_t)(blockIdx.y * 128) * K;
  const u16* Bb = B + (size_t)(blockIdx.x * 128) * K;
  const int c0 = (wid << 6) | lane;
  const int r0 = c0 >> 2, kc0 = (c0 & 3) << 3;
  const int c1 = c0 + 256;
  const int r1 = c1 >> 2, kc1 = (c1 & 3) << 3;

  f32x4 acc[4][4] = {};

  for (int k0 = 0; k0 < K; k0 += 32) {
    gld_lds16(Ab + (size_t)r0 * K + (k0 + kc0), &As[wid << 9]);
    gld_lds16(Ab + (size_t)r1 * K + (k0 + kc1), &As[2048 + (wid << 9)]);
    gld_lds16(Bb + (size_t)r0 * K + (k0 + kc0), &Bs[wid << 9]);
    gld_lds16(Bb + (size_t)r1 * K + (k0 + kc1), &Bs[2048 + (wid << 9)]);
    __syncthreads();
    bf16x8 av[4], bv[4];
#pragma unroll
    for (int t = 0; t < 4; t++)
      av[t] = *(const bf16x8*)&As[(wm * 64 + t * 16 + fr) * 32 + fk];
#pragma unroll
    for (int t = 0; t < 4; t++)
      bv[t] = *(const bf16x8*)&Bs[(wn * 64 + t * 16 + fr) * 32 + fk];
#pragma unroll
    for (int mt = 0; mt < 4; mt++)
#pragma unroll
      for (int nt = 0; nt < 4; nt++)
        acc[mt][nt] = __builtin_amdgcn_mfma_f32_16x16x32_bf16(av[mt], bv[nt], acc[mt][nt], 0, 0, 0);
    __syncthreads();
  }

  // C/D layout: col = lane&15 (+16*nt +64*wn), row = (lane>>4)*4 + reg (+16*mt +64*wm)
  const int lrow0 = wm * 64 + ((lane >> 4) << 2);
  const int lcol0 = wn * 64 + fr;

  if (MODE == 0) {
    const int bx = blockIdx.x, by = blockIdx.y;
    const bool isV = bx >= 6;
    // ---- write phase: BN fold + f2b -> LDS tile (row-major Q/K, col-major V)
#pragma unroll
    for (int nt = 0; nt < 4; nt++) {
      const int lc = lcol0 + nt * 16;
      const int gc = bx * 128 + lc;
      const float iv = inv[gc], of = off[gc];
#pragma unroll
      for (int mt = 0; mt < 4; mt++)
#pragma unroll
        for (int rg = 0; rg < 4; rg++) {
          const int lr = lrow0 + mt * 16 + rg;
          const u16 us = f2b(acc[mt][nt][rg] * iv + of);
          if (isV) lds[lc * TSTR + lr] = us;
          else     lds[lr * TSTR + lc] = us;
        }
    }
    __syncthreads();
    // ---- store phase: vector stores, block-uniform mapping
    if (!isV) {
      u16* dstB = (bx < 3) ? Qb : Kb;
      const int h0 = (bx < 3 ? bx : bx - 3) * 4;
#pragma unroll
      for (int it = 0; it < 8; it++) {
        const int idx = it * 256 + tid;
        const int ch = idx & 3, hl = (idx >> 2) & 3, row = idx >> 4;
        const int rowg = by * 128 + row;
        const int b = rowg / 196, n = rowg - b * 196;
        const size_t bh = (size_t)(b * NHD + h0 + hl);
        const u16* src = &lds[row * TSTR + hl * 32 + ch * 8];
        uint2 a0 = *(const uint2*)src;
        uint2 a1 = *(const uint2*)(src + 4);
        *(uint4*)(dstB + (bh * NQ + n) * 32 + ch * 8) = make_uint4(a0.x, a0.y, a1.x, a1.y);
      }
    } else {
      const int h = bx - 6;
#pragma unroll
      for (int it = 0; it < 16; it++) {
        const int idx = it * 256 + tid;
        const int nk = idx & 31, col = idx >> 5;
        const int rowg = by * 128 + nk * 4;       // 4 rows, never cross b (196 % 4 == 0)
        const int b = rowg / 196, n = rowg - b * 196;
        uint2 v = *(const uint2*)&lds[col * TSTR + nk * 4];
        // k-slot permutation: 4-col chunk cm = n/4 -> sm = 8*(cm>>3) + 2*(cm&3) + ((cm>>2)&1)
        const int kcB = n >> 5, r = (n >> 2) & 7;
        const int np = (kcB << 5) + ((((r & 3) << 1) + (r >> 2)) << 2);
        *(uint2*)(Vt + ((size_t)(b * NHD + h) * 128 + col) * VTS + np) = v;
      }
    }
  } else {
    const int colb = blockIdx.x * 128 + lcol0;
    const int rowb = blockIdx.y * 128 + lrow0;
#pragma unroll
    for (int nt = 0; nt < 4; nt++) {
      const int col = colb + nt * 16;
      const float iv = inv[col], of = off[col];
#pragma unroll
      for (int mt = 0; mt < 4; mt++)
#pragma unroll
        for (int rg = 0; rg < 4; rg++) {
          const int row = rowb + mt * 16 + rg;
          out[(size_t)row * DIMX + col] = acc[mt][nt][rg] * iv + of;
        }
    }
  }
}

// ---------------- MFMA tile attention + silu ----------------
// Swapped QK^T (mfma(K,Q)): lane holds P[q=rt*16+fr][k=16t+4*fj+rg] -> softmax is
// lane-local + 2 shfl_xor; P stays in registers. PV A-fragments are lane-local
// pairs under the k-slot permutation gemm0 pre-applied to Vt's n-columns.
// LDS: Ks 16.6 KB + Vs 59.4 KB = 76 KB -> 2 blocks/CU.
// Block = 384 threads (6 waves), launch_bounds(384,2) -> 2 blocks x 6 waves =
// 12 waves/CU = 3 waves/SIMD -> ~168-VGPR cap; peak live ~115, no spill.
// CORRECTNESS NOTE (r5 post-mortem): rinv lives in P-space (row q = fr). The PV
// output o[dt][rg] is row 4*fj+rg, so rinv MUST be applied to pf (P-space),
// never deferred to o (r5 normalized rows by the wrong denominators: absmax 0.111).

__global__ __launch_bounds__(384, 2) void attn_kernel(
    const u16* __restrict__ Qg, const u16* __restrict__ Kg,
    const u16* __restrict__ Vtg, const float* __restrict__ biasT,
    u16* __restrict__ AO) {
  __shared__ __align__(16) u16 Ks[208 * KSTR];
  __shared__ __align__(16) u16 Vs[128 * VSTR];

  const int tid = threadIdx.x, wid = tid >> 6, lane = tid & 63;
  const int fr = lane & 15, fj = lane >> 4, fk = fj << 3;
  const int bh = blockIdx.x, b = bh / NHD, h = bh - b * NHD;
  const float scale = 0.17677669529663687f;

  for (int i = tid; i < NQ * 4; i += 384) {
    const int m = i >> 2, kc = (i & 3) << 3;
    *(uint4*)&Ks[m * KSTR + kc] = *(const uint4*)(Kg + ((size_t)bh * NQ + m) * 32 + kc);
  }
  if (tid < 48) {  // zero K pad rows 196..207
    const int m = 196 + (tid >> 2), kc = (tid & 3) << 3;
    *(uint4*)&Ks[m * KSTR + kc] = make_uint4(0u, 0u, 0u, 0u);
  }
  {  // V stage: Vt rows are VTS=224 u16 (448 B = 28 x 16B), pad cols already zero
    const u16* Vb = Vtg + (size_t)bh * 128 * VTS;
    for (int i = tid; i < 128 * 28; i += 384) {
      const int d = i / 28, c = i - d * 28;
      *(uint4*)&Vs[d * VSTR + c * 8] = *(const uint4*)(Vb + (size_t)d * VTS + c * 8);
    }
  }
  __syncthreads();

  const float* bT = biasT + (size_t)h * BTS * BTS;

  for (int rt = wid; rt < 13; rt += 6) {
    int qrow = rt * 16 + fr; qrow = qrow > 195 ? 195 : qrow;
    const bf16x8 qf = *(const bf16x8*)(Qg + ((size_t)bh * NQ + qrow) * 32 + fk);

    // swapped QK^T: s[t][rg] = P[q = rt*16+fr][k = 16t + 4*fj + rg]
    f32x4 s[13];
#pragma unroll
    for (int t = 0; t < 13; t++) {
      const bf16x8 kf = *(const bf16x8*)&Ks[(t * 16 + fr) * KSTR + fk];
      f32x4 z = {0.f, 0.f, 0.f, 0.f};
      s[t] = __builtin_amdgcn_mfma_f32_16x16x32_bf16(kf, qf, z, 0, 0, 0);
    }

    // bias add: lane-local row q (rows >=196 are all -1e30 -> masked junk)
    const int q = rt * 16 + fr;
    const float* bRow = bT + (size_t)q * BTS + (fj << 2);
#pragma unroll
    for (int t = 0; t < 13; t++) {
      const float4 bv = *(const float4*)(bRow + t * 16);
      s[t][0] = s[t][0] * scale + bv.x;
      s[t][1] = s[t][1] * scale + bv.y;
      s[t][2] = s[t][2] * scale + bv.z;
      s[t][3] = s[t][3] * scale + bv.w;
    }

    // softmax over k: 52 lane-local values + partners at lane^16, lane^32
    float mx = fmaxf(fmaxf(s[0][0], s[0][1]), fmaxf(s[0][2], s[0][3]));
#pragma unroll
    for (int t = 1; t < 13; t++)
      mx = fmaxf(mx, fmaxf(fmaxf(s[t][0], s[t][1]), fmaxf(s[t][2], s[t][3])));
    mx = fmaxf(mx, __shfl_xor(mx, 16));
    mx = fmaxf(mx, __shfl_xor(mx, 32));
    float ls = 0.f;
#pragma unroll
    for (int t = 0; t < 13; t++)
#pragma unroll
      for (int rg = 0; rg < 4; rg++) {
        const float e = __expf(s[t][rg] - mx);
        s[t][rg] = e;
        ls += e;
      }
    ls += __shfl_xor(ls, 16);
    ls += __shfl_xor(ls, 32);
    const float rinv = 1.f / ls;

    // normalize + pack P to bf16 in P-SPACE (row = fr): frees s[] before PV
    bf16x8 pf[7];
#pragma unroll
    for (int kc = 0; kc < 7; kc++) {
      pf[kc][0] = (bf16_t)(s[2 * kc][0] * rinv);
      pf[kc][1] = (bf16_t)(s[2 * kc][1] * rinv);
      pf[kc][2] = (bf16_t)(s[2 * kc][2] * rinv);
      pf[kc][3] = (bf16_t)(s[2 * kc][3] * rinv);
      if (kc < 6) {
        pf[kc][4] = (bf16_t)(s[2 * kc + 1][0] * rinv);
        pf[kc][5] = (bf16_t)(s[2 * kc + 1][1] * rinv);
        pf[kc][6] = (bf16_t)(s[2 * kc + 1][2] * rinv);
        pf[kc][7] = (bf16_t)(s[2 * kc + 1][3] * rinv);
      } else {
        pf[kc][4] = (bf16_t)0.f; pf[kc][5] = (bf16_t)0.f;
        pf[kc][6] = (bf16_t)0.f; pf[kc][7] = (bf16_t)0.f;
      }
    }

    // PV: lane-local A fragments; Vs k-columns were permuted to match slot order
    f32x4 o[8] = {};
#pragma unroll
    for (int kc = 0; kc < 7; kc++) {
#pragma unroll
      for (int dt = 0; dt < 8; dt++) {
        const bf16x8 vf = *(const bf16x8*)&Vs[(dt * 16 + fr) * VSTR + kc * 32 + fk];
        o[dt] = __builtin_amdgcn_mfma_f32_16x16x32_bf16(pf[kc], vf, o[dt], 0, 0, 0);
      }
    }

    // store + silu: o[dt][rg] = O[q = rt*16+4*fj+rg][d = dt*16+fr], already normalized
#pragma unroll
    for (int rg = 0; rg < 4; rg++) {
      const int n = rt * 16 + fj * 4 + rg;
      if (n < 196) {
#pragma unroll
        for (int dt = 0; dt < 8; dt++) {
          float x = o[dt][rg];
          x = x / (1.f + __expf(-x));
          AO[((size_t)(b * NQ + n)) * VAD + h * 128 + dt * 16 + fr] = f2b(x);
        }
      }
    }
  }
}

// ---------------- host launcher ----------------

extern "C" void kernel_launch(void* const* d_in, const int* in_sizes, int n_in,
                              void* d_out, int out_size, void* d_ws, size_t ws_size,
                              hipStream_t stream) {
  const float* x          = (const float*)d_in[0];
  const float* qkv_w      = (const float*)d_in[1];
  const float* qkv_gamma  = (const float*)d_in[2];
  const float* qkv_beta   = (const float*)d_in[3];
  const float* qkv_mean   = (const float*)d_in[4];
  const float* qkv_var    = (const float*)d_in[5];
  const float* attn_bias  = (const float*)d_in[6];
  const float* proj_w     = (const float*)d_in[7];
  const float* proj_gamma = (const float*)d_in[8];
  const float* proj_beta  = (const float*)d_in[9];
  const float* proj_mean  = (const float*)d_in[10];
  const float* proj_var   = (const float*)d_in[11];

  const size_t szXB    = (size_t)MTOT * DIMX * 2;
  const size_t szQKVW  = (size_t)QKVD * DIMX * 2;
  const size_t szPROJW = (size_t)DIMX * VAD * 2;
  const size_t szQK    = (size_t)128 * NHD * NQ * 32 * 2;
  const size_t szV     = (size_t)128 * NHD * 128 * VTS * 2;
  const size_t szBT    = (size_t)NHD * BTS * BTS * 4;
  const size_t szAO    = (size_t)MTOT * VAD * 2;
  const size_t szX     = (szXB + szQKVW > szAO) ? (szXB + szQKVW) : szAO;

  char* w = (char*)d_ws;
  u16* projwb = (u16*)w; w += szPROJW;
  float* inv1 = (float*)w; w += QKVD * 4;
  float* off1 = (float*)w; w += QKVD * 4;
  float* inv2 = (float*)w; w += DIMX * 4;
  float* off2 = (float*)w; w += DIMX * 4;
  float* biasT = (float*)w; w += szBT;
  u16* Qb = (u16*)w; w += szQK;     // (B,H,N,32)
  u16* Kb = (u16*)w; w += szQK;     // (B,H,N,32)
  u16* Vt = (u16*)w; w += szV;      // (B,H,128,VTS) transposed, padded, k-permuted
  char* regionX = w; w += szX;
  u16* xb    = (u16*)regionX;
  u16* qkvwb = (u16*)(regionX + szXB);
  u16* AO    = (u16*)regionX;       // aliases xb/qkvwb (disjoint lifetimes)

  if ((size_t)(w - (char*)d_ws) > ws_size) return;

  cvt_kernel<<<MTOT * DIMX / 4 / 256, 256, 0, stream>>>(x, xb, MTOT * DIMX / 4);
  cvt_wqkv<<<(QKVD * DIMX / 4 + 255) / 256, 256, 0, stream>>>(qkv_w, qkvwb);
  cvt_kernel<<<DIMX * VAD / 4 / 256, 256, 0, stream>>>(proj_w, projwb, DIMX * VAD / 4);
  bn_tab_qkv<<<(QKVD + 255) / 256, 256, 0, stream>>>(qkv_gamma, qkv_beta, qkv_mean, qkv_var, inv1, off1);
  bn_tab<<<(DIMX + 255) / 256, 256, 0, stream>>>(proj_gamma, proj_beta, proj_mean, proj_var, inv2, off2, DIMX);
  bias_expand<<<(NHD * BTS * BTS + 255) / 256, 256, 0, stream>>>(attn_bias, biasT);
  pad_vt<<<(128 * NHD * 128 * 14 + 255) / 256, 256, 0, stream>>>(Vt);

  gemm_bt<0><<<dim3(QKVD / 128, MTOT / 128), 256, 0, stream>>>(
      xb, qkvwb, DIMX, inv1, off1, Qb, Kb, Vt, nullptr);
  attn_kernel<<<128 * NHD, 384, 0, stream>>>(Qb, Kb, Vt, biasT, AO);
  gemm_bt<1><<<dim3(DIMX / 128, MTOT / 128), 256, 0, stream>>>(
      AO, projwb, VAD, inv2, off2, nullptr, nullptr, nullptr, (float*)d_out);
}

// Round 8
// 524.895 us; speedup vs baseline: 1.0588x; 1.0588x over previous
//
#include <hip/hip_runtime.h>
#include <cstdint>

#define NQ 196
#define DIMX 384
#define QKVD 2304
#define VAD 1536
#define NHD 12
#define MTOT 25088  // 128*196

#define KSTR 40    // u16 stride of K tile in attn LDS
#define VSTR 232   // u16 stride of V^T rows in attn LDS
#define VTS 224    // u16 stride of Vt rows in global (padded, zero tail)
#define BTS 208    // f32 stride of expanded bias table
#define TSTR 140   // u16 stride of gemm0 epilogue LDS tile

typedef unsigned int u32;
typedef unsigned short u16;
typedef __bf16 bf16_t;
typedef bf16_t bf16x8 __attribute__((ext_vector_type(8)));
typedef float f32x4 __attribute__((ext_vector_type(4)));

__device__ inline u16 f2b(float f) {
  u32 u = __float_as_uint(f);
  u32 r = (u + 0x7fffu + ((u >> 16) & 1u)) >> 16;
  return (u16)r;
}
__device__ inline float b2f(u16 u) { return __uint_as_float(((u32)u) << 16); }
__device__ inline int iabs(int v) { return v < 0 ? -v : v; }

__device__ inline void gld_lds16(const void* g, void* l) {
  __builtin_amdgcn_global_load_lds((__attribute__((address_space(1))) void*)g,
                                   (__attribute__((address_space(3))) void*)l,
                                   16, 0, 0);
}

// ---------------- conversion / BN-table helpers ----------------

__global__ void cvt_kernel(const float* __restrict__ in, u16* __restrict__ out, int n4) {
  int i = blockIdx.x * 256 + threadIdx.x;
  if (i >= n4) return;
  float4 v = ((const float4*)in)[i];
  ushort4 o;
  o.x = f2b(v.x); o.y = f2b(v.y); o.z = f2b(v.z); o.w = f2b(v.w);
  ((ushort4*)out)[i] = o;
}

// QKV weight: bf16 + row reorder so new cols = [Q 12*32 | K 12*32 | V 12*128]
__global__ void cvt_wqkv(const float* __restrict__ in, u16* __restrict__ out) {
  int i = blockIdx.x * 256 + threadIdx.x;
  if (i >= QKVD * DIMX / 4) return;
  const int newc = i / (DIMX / 4);
  const int kc = (i - newc * (DIMX / 4)) * 4;
  int oldc;
  if (newc < 384)      { int h = newc >> 5;              oldc = h * 192 + (newc & 31); }
  else if (newc < 768) { int t = newc - 384; int h = t >> 5; oldc = h * 192 + 32 + (t & 31); }
  else                 { int t = newc - 768; int h = t >> 7; oldc = h * 192 + 64 + (t & 127); }
  float4 v = *(const float4*)(in + (size_t)oldc * DIMX + kc);
  ushort4 o;
  o.x = f2b(v.x); o.y = f2b(v.y); o.z = f2b(v.z); o.w = f2b(v.w);
  *(ushort4*)(out + (size_t)newc * DIMX + kc) = o;
}

__global__ void bn_tab(const float* __restrict__ g, const float* __restrict__ be,
                       const float* __restrict__ mn, const float* __restrict__ vr,
                       float* __restrict__ inv, float* __restrict__ off, int n) {
  int i = blockIdx.x * 256 + threadIdx.x;
  if (i >= n) return;
  float iv = g[i] * rsqrtf(vr[i] + 1e-5f);
  inv[i] = iv;
  off[i] = be[i] - mn[i] * iv;
}

// BN table for QKV, written in the reordered column order.
// Q columns (newc < 384) get the attention scale folded in: attn then computes
// pre-scaled logits directly in the QK^T MFMA (bias rides in the accumulator).
__global__ void bn_tab_qkv(const float* __restrict__ g, const float* __restrict__ be,
                           const float* __restrict__ mn, const float* __restrict__ vr,
                           float* __restrict__ inv, float* __restrict__ off) {
  int i = blockIdx.x * 256 + threadIdx.x;  // old column index
  if (i >= QKVD) return;
  const int h = i / 192, r = i - h * 192;
  const int newc = (r < 32) ? h * 32 + r
                 : (r < 64) ? 384 + h * 32 + (r - 32)
                            : 768 + h * 128 + (r - 64);
  float iv = g[i] * rsqrtf(vr[i] + 1e-5f);
  float of = be[i] - mn[i] * iv;
  if (newc < 384) {  // Q column: fold softmax scale
    const float scale = 0.17677669529663687f;
    iv *= scale;
    of *= scale;
  }
  inv[newc] = iv;
  off[newc] = of;
}

// Expanded bias table: biasT[h][m][n] = biases[h, |yn-ym|*14 + |xn-xm|],
// padded to 208x208 with -1e30 so it doubles as the validity mask.
__global__ void bias_expand(const float* __restrict__ biases, float* __restrict__ bt) {
  int i = blockIdx.x * 256 + threadIdx.x;
  if (i >= NHD * BTS * BTS) return;
  const int h = i / (BTS * BTS), r = i - h * BTS * BTS;
  const int m = r / BTS, n = r - m * BTS;
  float v = -1e30f;
  if (m < NQ && n < NQ) {
    const int ym = m / 14, xm = m - ym * 14;
    const int yn = n / 14, xn = n - yn * 14;
    v = biases[h * NQ + iabs(yn - ym) * 14 + iabs(xn - xm)];
  }
  bt[i] = v;
}

// Zero-fill the padded tail columns n in [196,224) of Vt so PV MFMA pads are NaN-free.
// (Zero chunks map onto all permuted pad slots; real chunk 192..195 is a fixed point.)
__global__ void pad_vt(u16* __restrict__ Vt) {
  int i = blockIdx.x * 256 + threadIdx.x;
  if (i >= 128 * NHD * 128 * 14) return;
  const int row = i / 14, c = i - row * 14;
  *(u32*)(Vt + (size_t)row * VTS + NQ + c * 2) = 0u;
}

// ---------------- bf16 MFMA GEMM, C = A * B^T (both K-contiguous) ----------------
// MODE 0: QKV (reordered cols). Epilogue: BN fold -> LDS tile -> vector stores.
//   blocks 0-2: Q (4 heads each), 3-5: K, 6-17: V (1 head each, stored transposed
//   (b,h,d,n) stride VTS, with n-columns PERMUTED within each 32-block so attn's
//   lane-local P fragments line up: slot 8*fj+j <-> true-n 32kc+16*(j>>2)+4*fj+(j&3)).
// MODE 1: proj epilogue (BN fold, fp32 out)

template <int MODE>
__global__ __launch_bounds__(256) void gemm_bt(
    const u16* __restrict__ A, const u16* __restrict__ B, int K,
    const float* __restrict__ inv, const float* __restrict__ off,
    u16* __restrict__ Qb, u16* __restrict__ Kb, u16* __restrict__ Vt,
    float* __restrict__ out) {
  constexpr int LDSU = (MODE == 0) ? 128 * TSTR : 8192;  // epilogue tile unions As/Bs
  __shared__ __align__(16) u16 lds[LDSU];
  u16* As = lds;
  u16* Bs = lds + 4096;
  const int tid = threadIdx.x;
  const int wid = tid >> 6, lane = tid & 63;
  const int wm = wid & 1, wn = wid >> 1;
  const int fr = lane & 15, fk = (lane >> 4) << 3;
  const u16* Ab = A + (size_t)(blockIdx.y * 128) * K;
  const u16* Bb = B + (size_t)(blockIdx.x * 128) * K;
  const int c0 = (wid << 6) | lane;
  const int r0 = c0 >> 2, kc0 = (c0 & 3) << 3;
  const int c1 = c0 + 256;
  const int r1 = c1 >> 2, kc1 = (c1 & 3) << 3;

  f32x4 acc[4][4] = {};

  for (int k0 = 0; k0 < K; k0 += 32) {
    gld_lds16(Ab + (size_t)r0 * K + (k0 + kc0), &As[wid << 9]);
    gld_lds16(Ab + (size_t)r1 * K + (k0 + kc1), &As[2048 + (wid << 9)]);
    gld_lds16(Bb + (size_t)r0 * K + (k0 + kc0), &Bs[wid << 9]);
    gld_lds16(Bb + (size_t)r1 * K + (k0 + kc1), &Bs[2048 + (wid << 9)]);
    __syncthreads();
    bf16x8 av[4], bv[4];
#pragma unroll
    for (int t = 0; t < 4; t++)
      av[t] = *(const bf16x8*)&As[(wm * 64 + t * 16 + fr) * 32 + fk];
#pragma unroll
    for (int t = 0; t < 4; t++)
      bv[t] = *(const bf16x8*)&Bs[(wn * 64 + t * 16 + fr) * 32 + fk];
#pragma unroll
    for (int mt = 0; mt < 4; mt++)
#pragma unroll
      for (int nt = 0; nt < 4; nt++)
        acc[mt][nt] = __builtin_amdgcn_mfma_f32_16x16x32_bf16(av[mt], bv[nt], acc[mt][nt], 0, 0, 0);
    __syncthreads();
  }

  // C/D layout: col = lane&15 (+16*nt +64*wn), row = (lane>>4)*4 + reg (+16*mt +64*wm)
  const int lrow0 = wm * 64 + ((lane >> 4) << 2);
  const int lcol0 = wn * 64 + fr;

  if (MODE == 0) {
    const int bx = blockIdx.x, by = blockIdx.y;
    const bool isV = bx >= 6;
    // ---- write phase: BN fold + f2b -> LDS tile (row-major Q/K, col-major V)
#pragma unroll
    for (int nt = 0; nt < 4; nt++) {
      const int lc = lcol0 + nt * 16;
      const int gc = bx * 128 + lc;
      const float iv = inv[gc], of = off[gc];
#pragma unroll
      for (int mt = 0; mt < 4; mt++)
#pragma unroll
        for (int rg = 0; rg < 4; rg++) {
          const int lr = lrow0 + mt * 16 + rg;
          const u16 us = f2b(acc[mt][nt][rg] * iv + of);
          if (isV) lds[lc * TSTR + lr] = us;
          else     lds[lr * TSTR + lc] = us;
        }
    }
    __syncthreads();
    // ---- store phase: vector stores, block-uniform mapping
    if (!isV) {
      u16* dstB = (bx < 3) ? Qb : Kb;
      const int h0 = (bx < 3 ? bx : bx - 3) * 4;
#pragma unroll
      for (int it = 0; it < 8; it++) {
        const int idx = it * 256 + tid;
        const int ch = idx & 3, hl = (idx >> 2) & 3, row = idx >> 4;
        const int rowg = by * 128 + row;
        const int b = rowg / 196, n = rowg - b * 196;
        const size_t bh = (size_t)(b * NHD + h0 + hl);
        const u16* src = &lds[row * TSTR + hl * 32 + ch * 8];
        uint2 a0 = *(const uint2*)src;
        uint2 a1 = *(const uint2*)(src + 4);
        *(uint4*)(dstB + (bh * NQ + n) * 32 + ch * 8) = make_uint4(a0.x, a0.y, a1.x, a1.y);
      }
    } else {
      const int h = bx - 6;
#pragma unroll
      for (int it = 0; it < 16; it++) {
        const int idx = it * 256 + tid;
        const int nk = idx & 31, col = idx >> 5;
        const int rowg = by * 128 + nk * 4;       // 4 rows, never cross b (196 % 4 == 0)
        const int b = rowg / 196, n = rowg - b * 196;
        uint2 v = *(const uint2*)&lds[col * TSTR + nk * 4];
        // k-slot permutation: 4-col chunk cm = n/4 -> sm = 8*(cm>>3) + 2*(cm&3) + ((cm>>2)&1)
        const int kcB = n >> 5, r = (n >> 2) & 7;
        const int np = (kcB << 5) + ((((r & 3) << 1) + (r >> 2)) << 2);
        *(uint2*)(Vt + ((size_t)(b * NHD + h) * 128 + col) * VTS + np) = v;
      }
    }
  } else {
    const int colb = blockIdx.x * 128 + lcol0;
    const int rowb = blockIdx.y * 128 + lrow0;
#pragma unroll
    for (int nt = 0; nt < 4; nt++) {
      const int col = colb + nt * 16;
      const float iv = inv[col], of = off[col];
#pragma unroll
      for (int mt = 0; mt < 4; mt++)
#pragma unroll
        for (int rg = 0; rg < 4; rg++) {
          const int row = rowb + mt * 16 + rg;
          out[(size_t)row * DIMX + col] = acc[mt][nt][rg] * iv + of;
        }
    }
  }
}

// ---------------- MFMA tile attention + silu ----------------
// Swapped QK^T (mfma(K,Q)): lane holds P[q=rt*16+fr][k=16t+4*fj+rg] -> softmax is
// lane-local + 2 shfl_xor; P stays in registers. PV A-fragments are lane-local
// pairs under the k-slot permutation gemm0 pre-applied to Vt's n-columns.
// BIAS-IN-ACCUMULATOR (r7): Q carries the softmax scale (folded in bn_tab_qkv),
// and each bias float4 initializes its MFMA's C operand -- the bias registers
// die into the accumulator. r4/r6 spilled the whole s[] every iteration because
// 52 bias regs + 52 s regs were live together under the 128-VGPR cap (VGPR
// wave-slots quantize at 64/128/256 per m69 -- there is no 170-reg allocation,
// so (384,2) still caps at 128).
// CORRECTNESS (r5): rinv lives in P-space (row q = fr); apply to pf, never to o.
// LDS: Ks 16.6 KB + Vs 59.4 KB = 76 KB -> 2 blocks/CU.

__global__ __launch_bounds__(384, 2) void attn_kernel(
    const u16* __restrict__ Qg, const u16* __restrict__ Kg,
    const u16* __restrict__ Vtg, const float* __restrict__ biasT,
    u16* __restrict__ AO) {
  __shared__ __align__(16) u16 Ks[208 * KSTR];
  __shared__ __align__(16) u16 Vs[128 * VSTR];

  const int tid = threadIdx.x, wid = tid >> 6, lane = tid & 63;
  const int fr = lane & 15, fj = lane >> 4, fk = fj << 3;
  const int bh = blockIdx.x, b = bh / NHD, h = bh - b * NHD;

  for (int i = tid; i < NQ * 4; i += 384) {
    const int m = i >> 2, kc = (i & 3) << 3;
    *(uint4*)&Ks[m * KSTR + kc] = *(const uint4*)(Kg + ((size_t)bh * NQ + m) * 32 + kc);
  }
  if (tid < 48) {  // zero K pad rows 196..207
    const int m = 196 + (tid >> 2), kc = (tid & 3) << 3;
    *(uint4*)&Ks[m * KSTR + kc] = make_uint4(0u, 0u, 0u, 0u);
  }
  {  // V stage: Vt rows are VTS=224 u16 (448 B = 28 x 16B), pad cols already zero
    const u16* Vb = Vtg + (size_t)bh * 128 * VTS;
    for (int i = tid; i < 128 * 28; i += 384) {
      const int d = i / 28, c = i - d * 28;
      *(uint4*)&Vs[d * VSTR + c * 8] = *(const uint4*)(Vb + (size_t)d * VTS + c * 8);
    }
  }
  __syncthreads();

  const float* bT = biasT + (size_t)h * BTS * BTS;

  for (int rt = wid; rt < 13; rt += 6) {
    int qrow = rt * 16 + fr; qrow = qrow > 195 ? 195 : qrow;
    const bf16x8 qf = *(const bf16x8*)(Qg + ((size_t)bh * NQ + qrow) * 32 + fk);

    // swapped QK^T with bias in C: s[t][rg] = (K.Q^T)[k][q] + bias[q][k]
    //   q = rt*16+fr, k = 16t + 4*fj + rg; Q is pre-scaled, so s is the logit.
    const int q = rt * 16 + fr;
    const float* bRow = bT + (size_t)q * BTS + (fj << 2);
    f32x4 s[13];
#pragma unroll
    for (int t = 0; t < 13; t++) {
      const bf16x8 kf = *(const bf16x8*)&Ks[(t * 16 + fr) * KSTR + fk];
      const f32x4 bz = *(const f32x4*)(bRow + t * 16);
      s[t] = __builtin_amdgcn_mfma_f32_16x16x32_bf16(kf, qf, bz, 0, 0, 0);
    }

    // softmax over k: 52 lane-local values + partners at lane^16, lane^32
    float mx = fmaxf(fmaxf(s[0][0], s[0][1]), fmaxf(s[0][2], s[0][3]));
#pragma unroll
    for (int t = 1; t < 13; t++)
      mx = fmaxf(mx, fmaxf(fmaxf(s[t][0], s[t][1]), fmaxf(s[t][2], s[t][3])));
    mx = fmaxf(mx, __shfl_xor(mx, 16));
    mx = fmaxf(mx, __shfl_xor(mx, 32));
    float ls = 0.f;
#pragma unroll
    for (int t = 0; t < 13; t++)
#pragma unroll
      for (int rg = 0; rg < 4; rg++) {
        const float e = __expf(s[t][rg] - mx);
        s[t][rg] = e;
        ls += e;
      }
    ls += __shfl_xor(ls, 16);
    ls += __shfl_xor(ls, 32);
    const float rinv = 1.f / ls;

    // normalize + pack P to bf16 in P-SPACE (row = fr): frees s[] before PV
    bf16x8 pf[7];
#pragma unroll
    for (int kc = 0; kc < 7; kc++) {
      pf[kc][0] = (bf16_t)(s[2 * kc][0] * rinv);
      pf[kc][1] = (bf16_t)(s[2 * kc][1] * rinv);
      pf[kc][2] = (bf16_t)(s[2 * kc][2] * rinv);
      pf[kc][3] = (bf16_t)(s[2 * kc][3] * rinv);
      if (kc < 6) {
        pf[kc][4] = (bf16_t)(s[2 * kc + 1][0] * rinv);
        pf[kc][5] = (bf16_t)(s[2 * kc + 1][1] * rinv);
        pf[kc][6] = (bf16_t)(s[2 * kc + 1][2] * rinv);
        pf[kc][7] = (bf16_t)(s[2 * kc + 1][3] * rinv);
      } else {
        pf[kc][4] = (bf16_t)0.f; pf[kc][5] = (bf16_t)0.f;
        pf[kc][6] = (bf16_t)0.f; pf[kc][7] = (bf16_t)0.f;
      }
    }

    // PV: lane-local A fragments; Vs k-columns were permuted to match slot order
    f32x4 o[8] = {};
#pragma unroll
    for (int kc = 0; kc < 7; kc++) {
#pragma unroll
      for (int dt = 0; dt < 8; dt++) {
        const bf16x8 vf = *(const bf16x8*)&Vs[(dt * 16 + fr) * VSTR + kc * 32 + fk];
        o[dt] = __builtin_amdgcn_mfma_f32_16x16x32_bf16(pf[kc], vf, o[dt], 0, 0, 0);
      }
    }

    // store + silu: o[dt][rg] = O[q = rt*16+4*fj+rg][d = dt*16+fr], already normalized
#pragma unroll
    for (int rg = 0; rg < 4; rg++) {
      const int n = rt * 16 + fj * 4 + rg;
      if (n < 196) {
#pragma unroll
        for (int dt = 0; dt < 8; dt++) {
          float x = o[dt][rg];
          x = x / (1.f + __expf(-x));
          AO[((size_t)(b * NQ + n)) * VAD + h * 128 + dt * 16 + fr] = f2b(x);
        }
      }
    }
  }
}

// ---------------- host launcher ----------------

extern "C" void kernel_launch(void* const* d_in, const int* in_sizes, int n_in,
                              void* d_out, int out_size, void* d_ws, size_t ws_size,
                              hipStream_t stream) {
  const float* x          = (const float*)d_in[0];
  const float* qkv_w      = (const float*)d_in[1];
  const float* qkv_gamma  = (const float*)d_in[2];
  const float* qkv_beta   = (const float*)d_in[3];
  const float* qkv_mean   = (const float*)d_in[4];
  const float* qkv_var    = (const float*)d_in[5];
  const float* attn_bias  = (const float*)d_in[6];
  const float* proj_w     = (const float*)d_in[7];
  const float* proj_gamma = (const float*)d_in[8];
  const float* proj_beta  = (const float*)d_in[9];
  const float* proj_mean  = (const float*)d_in[10];
  const float* proj_var   = (const float*)d_in[11];

  const size_t szXB    = (size_t)MTOT * DIMX * 2;
  const size_t szQKVW  = (size_t)QKVD * DIMX * 2;
  const size_t szPROJW = (size_t)DIMX * VAD * 2;
  const size_t szQK    = (size_t)128 * NHD * NQ * 32 * 2;
  const size_t szV     = (size_t)128 * NHD * 128 * VTS * 2;
  const size_t szBT    = (size_t)NHD * BTS * BTS * 4;
  const size_t szAO    = (size_t)MTOT * VAD * 2;
  const size_t szX     = (szXB + szQKVW > szAO) ? (szXB + szQKVW) : szAO;

  char* w = (char*)d_ws;
  u16* projwb = (u16*)w; w += szPROJW;
  float* inv1 = (float*)w; w += QKVD * 4;
  float* off1 = (float*)w; w += QKVD * 4;
  float* inv2 = (float*)w; w += DIMX * 4;
  float* off2 = (float*)w; w += DIMX * 4;
  float* biasT = (float*)w; w += szBT;
  u16* Qb = (u16*)w; w += szQK;     // (B,H,N,32)
  u16* Kb = (u16*)w; w += szQK;     // (B,H,N,32)
  u16* Vt = (u16*)w; w += szV;      // (B,H,128,VTS) transposed, padded, k-permuted
  char* regionX = w; w += szX;
  u16* xb    = (u16*)regionX;
  u16* qkvwb = (u16*)(regionX + szXB);
  u16* AO    = (u16*)regionX;       // aliases xb/qkvwb (disjoint lifetimes)

  if ((size_t)(w - (char*)d_ws) > ws_size) return;

  cvt_kernel<<<MTOT * DIMX / 4 / 256, 256, 0, stream>>>(x, xb, MTOT * DIMX / 4);
  cvt_wqkv<<<(QKVD * DIMX / 4 + 255) / 256, 256, 0, stream>>>(qkv_w, qkvwb);
  cvt_kernel<<<DIMX * VAD / 4 / 256, 256, 0, stream>>>(proj_w, projwb, DIMX * VAD / 4);
  bn_tab_qkv<<<(QKVD + 255) / 256, 256, 0, stream>>>(qkv_gamma, qkv_beta, qkv_mean, qkv_var, inv1, off1);
  bn_tab<<<(DIMX + 255) / 256, 256, 0, stream>>>(proj_gamma, proj_beta, proj_mean, proj_var, inv2, off2, DIMX);
  bias_expand<<<(NHD * BTS * BTS + 255) / 256, 256, 0, stream>>>(attn_bias, biasT);
  pad_vt<<<(128 * NHD * 128 * 14 + 255) / 256, 256, 0, stream>>>(Vt);

  gemm_bt<0><<<dim3(QKVD / 128, MTOT / 128), 256, 0, stream>>>(
      xb, qkvwb, DIMX, inv1, off1, Qb, Kb, Vt, nullptr);
  attn_kernel<<<128 * NHD, 384, 0, stream>>>(Qb, Kb, Vt, biasT, AO);
  gemm_bt<1><<<dim3(DIMX / 128, MTOT / 128), 256, 0, stream>>>(
      AO, projwb, VAD, inv2, off2, nullptr, nullptr, nullptr, (float*)d_out);
}

// Round 9
// 486.134 us; speedup vs baseline: 1.1432x; 1.0797x over previous
//
#include <hip/hip_runtime.h>
#include <cstdint>

#define NQ 196
#define DIMX 384
#define QKVD 2304
#define VAD 1536
#define NHD 12
#define MTOT 25088  // 128*196

#define KSTR 40    // u16 stride of K tile in attn LDS
#define VSTR 232   // u16 stride of V^T rows in attn LDS
#define VTS 224    // u16 stride of Vt rows in global (padded, zero tail)
#define BTS 208    // f32 stride of expanded bias table
#define TSTR 140   // u16 stride of gemm0 epilogue LDS tile

typedef unsigned int u32;
typedef unsigned short u16;
typedef __bf16 bf16_t;
typedef bf16_t bf16x8 __attribute__((ext_vector_type(8)));
typedef float f32x4 __attribute__((ext_vector_type(4)));

__device__ inline u16 f2b(float f) {
  u32 u = __float_as_uint(f);
  u32 r = (u + 0x7fffu + ((u >> 16) & 1u)) >> 16;
  return (u16)r;
}
__device__ inline float b2f(u16 u) { return __uint_as_float(((u32)u) << 16); }
__device__ inline int iabs(int v) { return v < 0 ? -v : v; }

__device__ inline void gld_lds16(const void* g, void* l) {
  __builtin_amdgcn_global_load_lds((__attribute__((address_space(1))) void*)g,
                                   (__attribute__((address_space(3))) void*)l,
                                   16, 0, 0);
}

// ---------------- conversion / BN-table helpers ----------------

__global__ void cvt_kernel(const float* __restrict__ in, u16* __restrict__ out, int n4) {
  int i = blockIdx.x * 256 + threadIdx.x;
  if (i >= n4) return;
  float4 v = ((const float4*)in)[i];
  ushort4 o;
  o.x = f2b(v.x); o.y = f2b(v.y); o.z = f2b(v.z); o.w = f2b(v.w);
  ((ushort4*)out)[i] = o;
}

// QKV weight: bf16 + row reorder so new cols = [Q 12*32 | K 12*32 | V 12*128]
__global__ void cvt_wqkv(const float* __restrict__ in, u16* __restrict__ out) {
  int i = blockIdx.x * 256 + threadIdx.x;
  if (i >= QKVD * DIMX / 4) return;
  const int newc = i / (DIMX / 4);
  const int kc = (i - newc * (DIMX / 4)) * 4;
  int oldc;
  if (newc < 384)      { int h = newc >> 5;              oldc = h * 192 + (newc & 31); }
  else if (newc < 768) { int t = newc - 384; int h = t >> 5; oldc = h * 192 + 32 + (t & 31); }
  else                 { int t = newc - 768; int h = t >> 7; oldc = h * 192 + 64 + (t & 127); }
  float4 v = *(const float4*)(in + (size_t)oldc * DIMX + kc);
  ushort4 o;
  o.x = f2b(v.x); o.y = f2b(v.y); o.z = f2b(v.z); o.w = f2b(v.w);
  *(ushort4*)(out + (size_t)newc * DIMX + kc) = o;
}

__global__ void bn_tab(const float* __restrict__ g, const float* __restrict__ be,
                       const float* __restrict__ mn, const float* __restrict__ vr,
                       float* __restrict__ inv, float* __restrict__ off, int n) {
  int i = blockIdx.x * 256 + threadIdx.x;
  if (i >= n) return;
  float iv = g[i] * rsqrtf(vr[i] + 1e-5f);
  inv[i] = iv;
  off[i] = be[i] - mn[i] * iv;
}

// BN table for QKV, written in the reordered column order.
// Q columns (newc < 384) get the attention scale folded in: attn then computes
// pre-scaled logits directly in the QK^T MFMA (bias rides in the accumulator).
__global__ void bn_tab_qkv(const float* __restrict__ g, const float* __restrict__ be,
                           const float* __restrict__ mn, const float* __restrict__ vr,
                           float* __restrict__ inv, float* __restrict__ off) {
  int i = blockIdx.x * 256 + threadIdx.x;  // old column index
  if (i >= QKVD) return;
  const int h = i / 192, r = i - h * 192;
  const int newc = (r < 32) ? h * 32 + r
                 : (r < 64) ? 384 + h * 32 + (r - 32)
                            : 768 + h * 128 + (r - 64);
  float iv = g[i] * rsqrtf(vr[i] + 1e-5f);
  float of = be[i] - mn[i] * iv;
  if (newc < 384) {  // Q column: fold softmax scale
    const float scale = 0.17677669529663687f;
    iv *= scale;
    of *= scale;
  }
  inv[newc] = iv;
  off[newc] = of;
}

// Expanded bias table: biasT[h][m][n] = biases[h, |yn-ym|*14 + |xn-xm|],
// padded to 208x208 with -1e30 so it doubles as the validity mask.
__global__ void bias_expand(const float* __restrict__ biases, float* __restrict__ bt) {
  int i = blockIdx.x * 256 + threadIdx.x;
  if (i >= NHD * BTS * BTS) return;
  const int h = i / (BTS * BTS), r = i - h * BTS * BTS;
  const int m = r / BTS, n = r - m * BTS;
  float v = -1e30f;
  if (m < NQ && n < NQ) {
    const int ym = m / 14, xm = m - ym * 14;
    const int yn = n / 14, xn = n - yn * 14;
    v = biases[h * NQ + iabs(yn - ym) * 14 + iabs(xn - xm)];
  }
  bt[i] = v;
}

// Zero-fill the padded tail columns n in [196,224) of Vt so PV MFMA pads are NaN-free.
// (Zero chunks map onto all permuted pad slots; real chunk 192..195 is a fixed point.)
__global__ void pad_vt(u16* __restrict__ Vt) {
  int i = blockIdx.x * 256 + threadIdx.x;
  if (i >= 128 * NHD * 128 * 14) return;
  const int row = i / 14, c = i - row * 14;
  *(u32*)(Vt + (size_t)row * VTS + NQ + c * 2) = 0u;
}

// ---------------- bf16 MFMA GEMM, C = A * B^T (both K-contiguous) ----------------
// MODE 0: QKV (reordered cols). Epilogue: BN fold -> LDS tile -> vector stores.
//   blocks 0-2: Q (4 heads each), 3-5: K, 6-17: V (1 head each, stored transposed
//   (b,h,d,n) stride VTS, with n-columns PERMUTED within each 32-block so attn's
//   lane-local P fragments line up: slot 8*fj+j <-> true-n 32kc+16*(j>>2)+4*fj+(j&3)).
// MODE 1: proj epilogue (BN fold, fp32 out)

template <int MODE>
__global__ __launch_bounds__(256) void gemm_bt(
    const u16* __restrict__ A, const u16* __restrict__ B, int K,
    const float* __restrict__ inv, const float* __restrict__ off,
    u16* __restrict__ Qb, u16* __restrict__ Kb, u16* __restrict__ Vt,
    float* __restrict__ out) {
  constexpr int LDSU = (MODE == 0) ? 128 * TSTR : 8192;  // epilogue tile unions As/Bs
  __shared__ __align__(16) u16 lds[LDSU];
  u16* As = lds;
  u16* Bs = lds + 4096;
  const int tid = threadIdx.x;
  const int wid = tid >> 6, lane = tid & 63;
  const int wm = wid & 1, wn = wid >> 1;
  const int fr = lane & 15, fk = (lane >> 4) << 3;
  const u16* Ab = A + (size_t)(blockIdx.y * 128) * K;
  const u16* Bb = B + (size_t)(blockIdx.x * 128) * K;
  const int c0 = (wid << 6) | lane;
  const int r0 = c0 >> 2, kc0 = (c0 & 3) << 3;
  const int c1 = c0 + 256;
  const int r1 = c1 >> 2, kc1 = (c1 & 3) << 3;

  f32x4 acc[4][4] = {};

  for (int k0 = 0; k0 < K; k0 += 32) {
    gld_lds16(Ab + (size_t)r0 * K + (k0 + kc0), &As[wid << 9]);
    gld_lds16(Ab + (size_t)r1 * K + (k0 + kc1), &As[2048 + (wid << 9)]);
    gld_lds16(Bb + (size_t)r0 * K + (k0 + kc0), &Bs[wid << 9]);
    gld_lds16(Bb + (size_t)r1 * K + (k0 + kc1), &Bs[2048 + (wid << 9)]);
    __syncthreads();
    bf16x8 av[4], bv[4];
#pragma unroll
    for (int t = 0; t < 4; t++)
      av[t] = *(const bf16x8*)&As[(wm * 64 + t * 16 + fr) * 32 + fk];
#pragma unroll
    for (int t = 0; t < 4; t++)
      bv[t] = *(const bf16x8*)&Bs[(wn * 64 + t * 16 + fr) * 32 + fk];
#pragma unroll
    for (int mt = 0; mt < 4; mt++)
#pragma unroll
      for (int nt = 0; nt < 4; nt++)
        acc[mt][nt] = __builtin_amdgcn_mfma_f32_16x16x32_bf16(av[mt], bv[nt], acc[mt][nt], 0, 0, 0);
    __syncthreads();
  }

  // C/D layout: col = lane&15 (+16*nt +64*wn), row = (lane>>4)*4 + reg (+16*mt +64*wm)
  const int lrow0 = wm * 64 + ((lane >> 4) << 2);
  const int lcol0 = wn * 64 + fr;

  if (MODE == 0) {
    const int bx = blockIdx.x, by = blockIdx.y;
    const bool isV = bx >= 6;
    // ---- write phase: BN fold + f2b -> LDS tile (row-major Q/K, col-major V)
#pragma unroll
    for (int nt = 0; nt < 4; nt++) {
      const int lc = lcol0 + nt * 16;
      const int gc = bx * 128 + lc;
      const float iv = inv[gc], of = off[gc];
#pragma unroll
      for (int mt = 0; mt < 4; mt++)
#pragma unroll
        for (int rg = 0; rg < 4; rg++) {
          const int lr = lrow0 + mt * 16 + rg;
          const u16 us = f2b(acc[mt][nt][rg] * iv + of);
          if (isV) lds[lc * TSTR + lr] = us;
          else     lds[lr * TSTR + lc] = us;
        }
    }
    __syncthreads();
    // ---- store phase: vector stores, block-uniform mapping
    if (!isV) {
      u16* dstB = (bx < 3) ? Qb : Kb;
      const int h0 = (bx < 3 ? bx : bx - 3) * 4;
#pragma unroll
      for (int it = 0; it < 8; it++) {
        const int idx = it * 256 + tid;
        const int ch = idx & 3, hl = (idx >> 2) & 3, row = idx >> 4;
        const int rowg = by * 128 + row;
        const int b = rowg / 196, n = rowg - b * 196;
        const size_t bh = (size_t)(b * NHD + h0 + hl);
        const u16* src = &lds[row * TSTR + hl * 32 + ch * 8];
        uint2 a0 = *(const uint2*)src;
        uint2 a1 = *(const uint2*)(src + 4);
        *(uint4*)(dstB + (bh * NQ + n) * 32 + ch * 8) = make_uint4(a0.x, a0.y, a1.x, a1.y);
      }
    } else {
      const int h = bx - 6;
#pragma unroll
      for (int it = 0; it < 16; it++) {
        const int idx = it * 256 + tid;
        const int nk = idx & 31, col = idx >> 5;
        const int rowg = by * 128 + nk * 4;       // 4 rows, never cross b (196 % 4 == 0)
        const int b = rowg / 196, n = rowg - b * 196;
        uint2 v = *(const uint2*)&lds[col * TSTR + nk * 4];
        // k-slot permutation: 4-col chunk cm = n/4 -> sm = 8*(cm>>3) + 2*(cm&3) + ((cm>>2)&1)
        const int kcB = n >> 5, r = (n >> 2) & 7;
        const int np = (kcB << 5) + ((((r & 3) << 1) + (r >> 2)) << 2);
        *(uint2*)(Vt + ((size_t)(b * NHD + h) * 128 + col) * VTS + np) = v;
      }
    }
  } else {
    const int colb = blockIdx.x * 128 + lcol0;
    const int rowb = blockIdx.y * 128 + lrow0;
#pragma unroll
    for (int nt = 0; nt < 4; nt++) {
      const int col = colb + nt * 16;
      const float iv = inv[col], of = off[col];
#pragma unroll
      for (int mt = 0; mt < 4; mt++)
#pragma unroll
        for (int rg = 0; rg < 4; rg++) {
          const int row = rowb + mt * 16 + rg;
          out[(size_t)row * DIMX + col] = acc[mt][nt][rg] * iv + of;
        }
    }
  }
}

// ---------------- MFMA tile attention + silu ----------------
// Swapped QK^T (mfma(K,Q)): lane holds P[q=rt*16+fr][k=16t+4*fj+rg] -> softmax is
// lane-local + 2 shfl_xor; P stays in registers. PV A-fragments are lane-local
// pairs under the k-slot permutation gemm0 pre-applied to Vt's n-columns.
// Bias rides in the QK^T accumulator (Q pre-scaled in bn_tab_qkv).
// REGISTER REGIME (r8 post-mortem): HW VGPR quantum is 64 -> per-SIMD allocations
// are 64/128/192/256. 3 waves/SIMD (r6/r8) caps at 128 (3x192>512) and the ~150-reg
// live set (s[52] + 13 clustered in-flight bias loads + o/pf/addressing) spilled
// ~240 MB/dispatch regardless of lifetime tricks. Fix: 256-thread blocks (4 waves),
// launch_bounds(256,2) -> 2 blocks/CU (LDS-bound anyway) = 8 waves/CU = 2 waves/SIMD
// -> 256-VGPR cap. Spill-free beats wave count.
// CORRECTNESS (r5): rinv lives in P-space (row q = fr); apply to pf, never to o.
// LDS: Ks 16.6 KB + Vs 59.4 KB = 76 KB -> 2 blocks/CU.

__global__ __launch_bounds__(256, 2) void attn_kernel(
    const u16* __restrict__ Qg, const u16* __restrict__ Kg,
    const u16* __restrict__ Vtg, const float* __restrict__ biasT,
    u16* __restrict__ AO) {
  __shared__ __align__(16) u16 Ks[208 * KSTR];
  __shared__ __align__(16) u16 Vs[128 * VSTR];

  const int tid = threadIdx.x, wid = tid >> 6, lane = tid & 63;
  const int fr = lane & 15, fj = lane >> 4, fk = fj << 3;
  const int bh = blockIdx.x, b = bh / NHD, h = bh - b * NHD;

  for (int i = tid; i < NQ * 4; i += 256) {
    const int m = i >> 2, kc = (i & 3) << 3;
    *(uint4*)&Ks[m * KSTR + kc] = *(const uint4*)(Kg + ((size_t)bh * NQ + m) * 32 + kc);
  }
  if (tid < 48) {  // zero K pad rows 196..207
    const int m = 196 + (tid >> 2), kc = (tid & 3) << 3;
    *(uint4*)&Ks[m * KSTR + kc] = make_uint4(0u, 0u, 0u, 0u);
  }
  {  // V stage: Vt rows are VTS=224 u16 (448 B = 28 x 16B), pad cols already zero
    const u16* Vb = Vtg + (size_t)bh * 128 * VTS;
    for (int i = tid; i < 128 * 28; i += 256) {
      const int d = i / 28, c = i - d * 28;
      *(uint4*)&Vs[d * VSTR + c * 8] = *(const uint4*)(Vb + (size_t)d * VTS + c * 8);
    }
  }
  __syncthreads();

  const float* bT = biasT + (size_t)h * BTS * BTS;

  for (int rt = wid; rt < 13; rt += 4) {
    int qrow = rt * 16 + fr; qrow = qrow > 195 ? 195 : qrow;
    const bf16x8 qf = *(const bf16x8*)(Qg + ((size_t)bh * NQ + qrow) * 32 + fk);

    // swapped QK^T with bias in C: s[t][rg] = (K.Q^T)[k][q] + bias[q][k]
    //   q = rt*16+fr, k = 16t + 4*fj + rg; Q is pre-scaled, so s is the logit.
    const int q = rt * 16 + fr;
    const float* bRow = bT + (size_t)q * BTS + (fj << 2);
    f32x4 s[13];
#pragma unroll
    for (int t = 0; t < 13; t++) {
      const bf16x8 kf = *(const bf16x8*)&Ks[(t * 16 + fr) * KSTR + fk];
      const f32x4 bz = *(const f32x4*)(bRow + t * 16);
      s[t] = __builtin_amdgcn_mfma_f32_16x16x32_bf16(kf, qf, bz, 0, 0, 0);
    }

    // softmax over k: 52 lane-local values + partners at lane^16, lane^32
    float mx = fmaxf(fmaxf(s[0][0], s[0][1]), fmaxf(s[0][2], s[0][3]));
#pragma unroll
    for (int t = 1; t < 13; t++)
      mx = fmaxf(mx, fmaxf(fmaxf(s[t][0], s[t][1]), fmaxf(s[t][2], s[t][3])));
    mx = fmaxf(mx, __shfl_xor(mx, 16));
    mx = fmaxf(mx, __shfl_xor(mx, 32));
    float ls = 0.f;
#pragma unroll
    for (int t = 0; t < 13; t++)
#pragma unroll
      for (int rg = 0; rg < 4; rg++) {
        const float e = __expf(s[t][rg] - mx);
        s[t][rg] = e;
        ls += e;
      }
    ls += __shfl_xor(ls, 16);
    ls += __shfl_xor(ls, 32);
    const float rinv = 1.f / ls;

    // normalize + pack P to bf16 in P-SPACE (row = fr): frees s[] before PV
    bf16x8 pf[7];
#pragma unroll
    for (int kc = 0; kc < 7; kc++) {
      pf[kc][0] = (bf16_t)(s[2 * kc][0] * rinv);
      pf[kc][1] = (bf16_t)(s[2 * kc][1] * rinv);
      pf[kc][2] = (bf16_t)(s[2 * kc][2] * rinv);
      pf[kc][3] = (bf16_t)(s[2 * kc][3] * rinv);
      if (kc < 6) {
        pf[kc][4] = (bf16_t)(s[2 * kc + 1][0] * rinv);
        pf[kc][5] = (bf16_t)(s[2 * kc + 1][1] * rinv);
        pf[kc][6] = (bf16_t)(s[2 * kc + 1][2] * rinv);
        pf[kc][7] = (bf16_t)(s[2 * kc + 1][3] * rinv);
      } else {
        pf[kc][4] = (bf16_t)0.f; pf[kc][5] = (bf16_t)0.f;
        pf[kc][6] = (bf16_t)0.f; pf[kc][7] = (bf16_t)0.f;
      }
    }

    // PV: lane-local A fragments; Vs k-columns were permuted to match slot order
    f32x4 o[8] = {};
#pragma unroll
    for (int kc = 0; kc < 7; kc++) {
#pragma unroll
      for (int dt = 0; dt < 8; dt++) {
        const bf16x8 vf = *(const bf16x8*)&Vs[(dt * 16 + fr) * VSTR + kc * 32 + fk];
        o[dt] = __builtin_amdgcn_mfma_f32_16x16x32_bf16(pf[kc], vf, o[dt], 0, 0, 0);
      }
    }

    // store + silu: o[dt][rg] = O[q = rt*16+4*fj+rg][d = dt*16+fr], already normalized
#pragma unroll
    for (int rg = 0; rg < 4; rg++) {
      const int n = rt * 16 + fj * 4 + rg;
      if (n < 196) {
#pragma unroll
        for (int dt = 0; dt < 8; dt++) {
          float x = o[dt][rg];
          x = x / (1.f + __expf(-x));
          AO[((size_t)(b * NQ + n)) * VAD + h * 128 + dt * 16 + fr] = f2b(x);
        }
      }
    }
  }
}

// ---------------- host launcher ----------------

extern "C" void kernel_launch(void* const* d_in, const int* in_sizes, int n_in,
                              void* d_out, int out_size, void* d_ws, size_t ws_size,
                              hipStream_t stream) {
  const float* x          = (const float*)d_in[0];
  const float* qkv_w      = (const float*)d_in[1];
  const float* qkv_gamma  = (const float*)d_in[2];
  const float* qkv_beta   = (const float*)d_in[3];
  const float* qkv_mean   = (const float*)d_in[4];
  const float* qkv_var    = (const float*)d_in[5];
  const float* attn_bias  = (const float*)d_in[6];
  const float* proj_w     = (const float*)d_in[7];
  const float* proj_gamma = (const float*)d_in[8];
  const float* proj_beta  = (const float*)d_in[9];
  const float* proj_mean  = (const float*)d_in[10];
  const float* proj_var   = (const float*)d_in[11];

  const size_t szXB    = (size_t)MTOT * DIMX * 2;
  const size_t szQKVW  = (size_t)QKVD * DIMX * 2;
  const size_t szPROJW = (size_t)DIMX * VAD * 2;
  const size_t szQK    = (size_t)128 * NHD * NQ * 32 * 2;
  const size_t szV     = (size_t)128 * NHD * 128 * VTS * 2;
  const size_t szBT    = (size_t)NHD * BTS * BTS * 4;
  const size_t szAO    = (size_t)MTOT * VAD * 2;
  const size_t szX     = (szXB + szQKVW > szAO) ? (szXB + szQKVW) : szAO;

  char* w = (char*)d_ws;
  u16* projwb = (u16*)w; w += szPROJW;
  float* inv1 = (float*)w; w += QKVD * 4;
  float* off1 = (float*)w; w += QKVD * 4;
  float* inv2 = (float*)w; w += DIMX * 4;
  float* off2 = (float*)w; w += DIMX * 4;
  float* biasT = (float*)w; w += szBT;
  u16* Qb = (u16*)w; w += szQK;     // (B,H,N,32)
  u16* Kb = (u16*)w; w += szQK;     // (B,H,N,32)
  u16* Vt = (u16*)w; w += szV;      // (B,H,128,VTS) transposed, padded, k-permuted
  char* regionX = w; w += szX;
  u16* xb    = (u16*)regionX;
  u16* qkvwb = (u16*)(regionX + szXB);
  u16* AO    = (u16*)regionX;       // aliases xb/qkvwb (disjoint lifetimes)

  if ((size_t)(w - (char*)d_ws) > ws_size) return;

  cvt_kernel<<<MTOT * DIMX / 4 / 256, 256, 0, stream>>>(x, xb, MTOT * DIMX / 4);
  cvt_wqkv<<<(QKVD * DIMX / 4 + 255) / 256, 256, 0, stream>>>(qkv_w, qkvwb);
  cvt_kernel<<<DIMX * VAD / 4 / 256, 256, 0, stream>>>(proj_w, projwb, DIMX * VAD / 4);
  bn_tab_qkv<<<(QKVD + 255) / 256, 256, 0, stream>>>(qkv_gamma, qkv_beta, qkv_mean, qkv_var, inv1, off1);
  bn_tab<<<(DIMX + 255) / 256, 256, 0, stream>>>(proj_gamma, proj_beta, proj_mean, proj_var, inv2, off2, DIMX);
  bias_expand<<<(NHD * BTS * BTS + 255) / 256, 256, 0, stream>>>(attn_bias, biasT);
  pad_vt<<<(128 * NHD * 128 * 14 + 255) / 256, 256, 0, stream>>>(Vt);

  gemm_bt<0><<<dim3(QKVD / 128, MTOT / 128), 256, 0, stream>>>(
      xb, qkvwb, DIMX, inv1, off1, Qb, Kb, Vt, nullptr);
  attn_kernel<<<128 * NHD, 256, 0, stream>>>(Qb, Kb, Vt, biasT, AO);
  gemm_bt<1><<<dim3(DIMX / 128, MTOT / 128), 256, 0, stream>>>(
      AO, projwb, VAD, inv2, off2, nullptr, nullptr, nullptr, (float*)d_out);
}

// Round 10
// 393.254 us; speedup vs baseline: 1.4132x; 1.2362x over previous
//
#include <hip/hip_runtime.h>
#include <cstdint>

#define NQ 196
#define DIMX 384
#define QKVD 2304
#define VAD 1536
#define NHD 12
#define MTOT 25088  // 128*196

#define KSTR 40    // u16 stride of K tile in attn LDS
#define VSTR 232   // u16 stride of V^T rows and P strips in attn LDS
#define VTS 224    // u16 stride of Vt rows in global (padded, zero tail)
#define BTS 208    // f32 stride of expanded bias table
#define TSTR 140   // u16 stride of gemm0 epilogue LDS tile

typedef unsigned int u32;
typedef unsigned short u16;
typedef __bf16 bf16_t;
typedef bf16_t bf16x8 __attribute__((ext_vector_type(8)));
typedef float f32x4 __attribute__((ext_vector_type(4)));

__device__ inline u16 f2b(float f) {
  u32 u = __float_as_uint(f);
  u32 r = (u + 0x7fffu + ((u >> 16) & 1u)) >> 16;
  return (u16)r;
}
__device__ inline float b2f(u16 u) { return __uint_as_float(((u32)u) << 16); }
__device__ inline int iabs(int v) { return v < 0 ? -v : v; }

__device__ inline void gld_lds16(const void* g, void* l) {
  __builtin_amdgcn_global_load_lds((__attribute__((address_space(1))) void*)g,
                                   (__attribute__((address_space(3))) void*)l,
                                   16, 0, 0);
}

// ---------------- conversion / BN-table helpers ----------------

__global__ void cvt_kernel(const float* __restrict__ in, u16* __restrict__ out, int n4) {
  int i = blockIdx.x * 256 + threadIdx.x;
  if (i >= n4) return;
  float4 v = ((const float4*)in)[i];
  ushort4 o;
  o.x = f2b(v.x); o.y = f2b(v.y); o.z = f2b(v.z); o.w = f2b(v.w);
  ((ushort4*)out)[i] = o;
}

// QKV weight: bf16 + row reorder so new cols = [Q 12*32 | K 12*32 | V 12*128]
__global__ void cvt_wqkv(const float* __restrict__ in, u16* __restrict__ out) {
  int i = blockIdx.x * 256 + threadIdx.x;
  if (i >= QKVD * DIMX / 4) return;
  const int newc = i / (DIMX / 4);
  const int kc = (i - newc * (DIMX / 4)) * 4;
  int oldc;
  if (newc < 384)      { int h = newc >> 5;              oldc = h * 192 + (newc & 31); }
  else if (newc < 768) { int t = newc - 384; int h = t >> 5; oldc = h * 192 + 32 + (t & 31); }
  else                 { int t = newc - 768; int h = t >> 7; oldc = h * 192 + 64 + (t & 127); }
  float4 v = *(const float4*)(in + (size_t)oldc * DIMX + kc);
  ushort4 o;
  o.x = f2b(v.x); o.y = f2b(v.y); o.z = f2b(v.z); o.w = f2b(v.w);
  *(ushort4*)(out + (size_t)newc * DIMX + kc) = o;
}

__global__ void bn_tab(const float* __restrict__ g, const float* __restrict__ be,
                       const float* __restrict__ mn, const float* __restrict__ vr,
                       float* __restrict__ inv, float* __restrict__ off, int n) {
  int i = blockIdx.x * 256 + threadIdx.x;
  if (i >= n) return;
  float iv = g[i] * rsqrtf(vr[i] + 1e-5f);
  inv[i] = iv;
  off[i] = be[i] - mn[i] * iv;
}

// BN table for QKV, written in the reordered column order.
// Q columns (newc < 384) get the attention scale folded in: attn then gets
// pre-scaled logits directly out of the QK^T MFMA (bias rides in the C operand).
__global__ void bn_tab_qkv(const float* __restrict__ g, const float* __restrict__ be,
                           const float* __restrict__ mn, const float* __restrict__ vr,
                           float* __restrict__ inv, float* __restrict__ off) {
  int i = blockIdx.x * 256 + threadIdx.x;  // old column index
  if (i >= QKVD) return;
  const int h = i / 192, r = i - h * 192;
  const int newc = (r < 32) ? h * 32 + r
                 : (r < 64) ? 384 + h * 32 + (r - 32)
                            : 768 + h * 128 + (r - 64);
  float iv = g[i] * rsqrtf(vr[i] + 1e-5f);
  float of = be[i] - mn[i] * iv;
  if (newc < 384) {  // Q column: fold softmax scale
    const float scale = 0.17677669529663687f;
    iv *= scale;
    of *= scale;
  }
  inv[newc] = iv;
  off[newc] = of;
}

// Expanded bias table: biasT[h][m][n] = biases[h, |ym-yn|*14 + |xm-xn|] (symmetric),
// padded to 208x208 with -1e30 so it doubles as the validity mask.
__global__ void bias_expand(const float* __restrict__ biases, float* __restrict__ bt) {
  int i = blockIdx.x * 256 + threadIdx.x;
  if (i >= NHD * BTS * BTS) return;
  const int h = i / (BTS * BTS), r = i - h * BTS * BTS;
  const int m = r / BTS, n = r - m * BTS;
  float v = -1e30f;
  if (m < NQ && n < NQ) {
    const int ym = m / 14, xm = m - ym * 14;
    const int yn = n / 14, xn = n - yn * 14;
    v = biases[h * NQ + iabs(yn - ym) * 14 + iabs(xn - xm)];
  }
  bt[i] = v;
}

// Zero-fill the padded tail columns n in [196,224) of Vt so PV MFMA pads are NaN-free.
__global__ void pad_vt(u16* __restrict__ Vt) {
  int i = blockIdx.x * 256 + threadIdx.x;
  if (i >= 128 * NHD * 128 * 14) return;
  const int row = i / 14, c = i - row * 14;
  *(u32*)(Vt + (size_t)row * VTS + NQ + c * 2) = 0u;
}

// ---------------- bf16 MFMA GEMM, C = A * B^T (both K-contiguous) ----------------
// MODE 0: QKV (reordered cols). Epilogue: BN fold -> LDS tile -> vector stores.
//   blocks 0-2: Q (4 heads each), 3-5: K, 6-17: V (1 head each, stored transposed
//   (b,h,d,n) stride VTS, natural n order).
// MODE 1: proj epilogue (BN fold, fp32 out)

template <int MODE>
__global__ __launch_bounds__(256) void gemm_bt(
    const u16* __restrict__ A, const u16* __restrict__ B, int K,
    const float* __restrict__ inv, const float* __restrict__ off,
    u16* __restrict__ Qb, u16* __restrict__ Kb, u16* __restrict__ Vt,
    float* __restrict__ out) {
  constexpr int LDSU = (MODE == 0) ? 128 * TSTR : 8192;  // epilogue tile unions As/Bs
  __shared__ __align__(16) u16 lds[LDSU];
  u16* As = lds;
  u16* Bs = lds + 4096;
  const int tid = threadIdx.x;
  const int wid = tid >> 6, lane = tid & 63;
  const int wm = wid & 1, wn = wid >> 1;
  const int fr = lane & 15, fk = (lane >> 4) << 3;
  const u16* Ab = A + (size_t)(blockIdx.y * 128) * K;
  const u16* Bb = B + (size_t)(blockIdx.x * 128) * K;
  const int c0 = (wid << 6) | lane;
  const int r0 = c0 >> 2, kc0 = (c0 & 3) << 3;
  const int c1 = c0 + 256;
  const int r1 = c1 >> 2, kc1 = (c1 & 3) << 3;

  f32x4 acc[4][4] = {};

  for (int k0 = 0; k0 < K; k0 += 32) {
    gld_lds16(Ab + (size_t)r0 * K + (k0 + kc0), &As[wid << 9]);
    gld_lds16(Ab + (size_t)r1 * K + (k0 + kc1), &As[2048 + (wid << 9)]);
    gld_lds16(Bb + (size_t)r0 * K + (k0 + kc0), &Bs[wid << 9]);
    gld_lds16(Bb + (size_t)r1 * K + (k0 + kc1), &Bs[2048 + (wid << 9)]);
    __syncthreads();
    bf16x8 av[4], bv[4];
#pragma unroll
    for (int t = 0; t < 4; t++)
      av[t] = *(const bf16x8*)&As[(wm * 64 + t * 16 + fr) * 32 + fk];
#pragma unroll
    for (int t = 0; t < 4; t++)
      bv[t] = *(const bf16x8*)&Bs[(wn * 64 + t * 16 + fr) * 32 + fk];
#pragma unroll
    for (int mt = 0; mt < 4; mt++)
#pragma unroll
      for (int nt = 0; nt < 4; nt++)
        acc[mt][nt] = __builtin_amdgcn_mfma_f32_16x16x32_bf16(av[mt], bv[nt], acc[mt][nt], 0, 0, 0);
    __syncthreads();
  }

  // C/D layout: col = lane&15 (+16*nt +64*wn), row = (lane>>4)*4 + reg (+16*mt +64*wm)
  const int lrow0 = wm * 64 + ((lane >> 4) << 2);
  const int lcol0 = wn * 64 + fr;

  if (MODE == 0) {
    const int bx = blockIdx.x, by = blockIdx.y;
    const bool isV = bx >= 6;
    // ---- write phase: BN fold + f2b -> LDS tile (row-major Q/K, col-major V)
#pragma unroll
    for (int nt = 0; nt < 4; nt++) {
      const int lc = lcol0 + nt * 16;
      const int gc = bx * 128 + lc;
      const float iv = inv[gc], of = off[gc];
#pragma unroll
      for (int mt = 0; mt < 4; mt++)
#pragma unroll
        for (int rg = 0; rg < 4; rg++) {
          const int lr = lrow0 + mt * 16 + rg;
          const u16 us = f2b(acc[mt][nt][rg] * iv + of);
          if (isV) lds[lc * TSTR + lr] = us;
          else     lds[lr * TSTR + lc] = us;
        }
    }
    __syncthreads();
    // ---- store phase: vector stores, block-uniform mapping
    if (!isV) {
      u16* dstB = (bx < 3) ? Qb : Kb;
      const int h0 = (bx < 3 ? bx : bx - 3) * 4;
#pragma unroll
      for (int it = 0; it < 8; it++) {
        const int idx = it * 256 + tid;
        const int ch = idx & 3, hl = (idx >> 2) & 3, row = idx >> 4;
        const int rowg = by * 128 + row;
        const int b = rowg / 196, n = rowg - b * 196;
        const size_t bh = (size_t)(b * NHD + h0 + hl);
        const u16* src = &lds[row * TSTR + hl * 32 + ch * 8];
        uint2 a0 = *(const uint2*)src;
        uint2 a1 = *(const uint2*)(src + 4);
        *(uint4*)(dstB + (bh * NQ + n) * 32 + ch * 8) = make_uint4(a0.x, a0.y, a1.x, a1.y);
      }
    } else {
      const int h = bx - 6;
#pragma unroll
      for (int it = 0; it < 16; it++) {
        const int idx = it * 256 + tid;
        const int nk = idx & 31, col = idx >> 5;
        const int rowg = by * 128 + nk * 4;       // 4 rows, never cross b (196 % 4 == 0)
        const int b = rowg / 196, n = rowg - b * 196;
        uint2 v = *(const uint2*)&lds[col * TSTR + nk * 4];
        *(uint2*)(Vt + ((size_t)(b * NHD + h) * 128 + col) * VTS + n) = v;
      }
    }
  } else {
    const int colb = blockIdx.x * 128 + lcol0;
    const int rowb = blockIdx.y * 128 + lrow0;
#pragma unroll
    for (int nt = 0; nt < 4; nt++) {
      const int col = colb + nt * 16;
      const float iv = inv[col], of = off[col];
#pragma unroll
      for (int mt = 0; mt < 4; mt++)
#pragma unroll
        for (int rg = 0; rg < 4; rg++) {
          const int row = rowb + mt * 16 + rg;
          out[(size_t)row * DIMX + col] = acc[mt][nt][rg] * iv + of;
        }
    }
  }
}

// ---------------- MFMA tile attention + silu (r2 structure, VALU-trimmed) ----------------
// Base = round-2 kernel (115 us, 92 VGPR, no spill, traffic at ideal). Two changes:
// 1) BIAS-IN-ACCUMULATOR: Q pre-scaled (bn_tab_qkv); the bias float4
//    biasT[t*16+fr][rt*16+4fj..+3] is exactly the mfma C operand for
//    (row=4fj+rg -> q, col=fr -> k, via biasT symmetry). Deletes 52 FMA/iter.
// 2) NO MAX-SUBTRACTION: logits are BN-bounded (|logit| << 10; overflow needs >88
//    = ~440 sigma). Pads exact: K-pad rows zero + bias -1e30 -> exp = 0. Invalid
//    q-rows (>=196) give ls=0 -> rinv=inf -> NaN only in stores masked by n<196.
//    Deletes 48 fmax + 52 sub + 16 shfl per iter.
// rinv[rg] is indexed by OUTPUT row (q = rt*16+4fj+rg) and applied post-PV --
// legal here because P's rows in Ps are q-local 4fj+rg (unlike the swapped layout;
// r5 lesson). LDS: Ks 16.6 + Vs 59.4 + Ps 59.4 = 135.4 KB -> 1 block/CU.

__global__ __launch_bounds__(512) void attn_kernel(
    const u16* __restrict__ Qg, const u16* __restrict__ Kg,
    const u16* __restrict__ Vtg, const float* __restrict__ biasT,
    u16* __restrict__ AO) {
  __shared__ __align__(16) u16 Ks[208 * KSTR];
  __shared__ __align__(16) u16 Vs[128 * VSTR];
  __shared__ __align__(16) u16 Ps[8][16 * VSTR];

  const int tid = threadIdx.x, wid = tid >> 6, lane = tid & 63;
  const int fr = lane & 15, fj = lane >> 4, fk = fj << 3;
  const int bh = blockIdx.x, b = bh / NHD, h = bh - b * NHD;

  for (int i = tid; i < NQ * 4; i += 512) {
    const int m = i >> 2, kc = (i & 3) << 3;
    *(uint4*)&Ks[m * KSTR + kc] = *(const uint4*)(Kg + ((size_t)bh * NQ + m) * 32 + kc);
  }
  if (tid < 48) {  // zero K pad rows 196..207 (uninitialized LDS could hold NaN bits)
    const int m = 196 + (tid >> 2), kc = (tid & 3) << 3;
    *(uint4*)&Ks[m * KSTR + kc] = make_uint4(0u, 0u, 0u, 0u);
  }
  {  // V stage: Vt rows are VTS=224 u16 (448 B = 28 x 16B), pad cols already zero
    const u16* Vb = Vtg + (size_t)bh * 128 * VTS;
    for (int i = tid; i < 128 * 28; i += 512) {
      const int d = i / 28, c = i - d * 28;
      *(uint4*)&Vs[d * VSTR + c * 8] = *(const uint4*)(Vb + (size_t)d * VTS + c * 8);
    }
  }
  {  // zero P pad cols 208..223 (never rewritten)
    const int row = lane >> 2, c = 208 + (lane & 3) * 4;
    *(uint2*)&Ps[wid][row * VSTR + c] = make_uint2(0u, 0u);
  }
  __syncthreads();

  const float* bT = biasT + (size_t)h * BTS * BTS;

  for (int rt = wid; rt < 13; rt += 8) {
    int qrow = rt * 16 + fr; qrow = qrow > 195 ? 195 : qrow;
    const bf16x8 qf = *(const bf16x8*)(Qg + ((size_t)bh * NQ + qrow) * 32 + fk);

    // QK^T with bias in C: s[t][rg] = logit[q = rt*16+4fj+rg][k = t*16+fr]
    const int n0 = rt * 16 + (fj << 2);
    const float* bRow = bT + n0;
    f32x4 s[13];
#pragma unroll
    for (int t = 0; t < 13; t++) {
      const bf16x8 kf = *(const bf16x8*)&Ks[(t * 16 + fr) * KSTR + fk];
      const f32x4 bz = *(const f32x4*)(bRow + (size_t)(t * 16 + fr) * BTS);
      s[t] = __builtin_amdgcn_mfma_f32_16x16x32_bf16(qf, kf, bz, 0, 0, 0);
    }

    // softmax denominators, no max-sub: ls[rg] = sum_k exp(logit)
    float rinv[4];
#pragma unroll
    for (int rg = 0; rg < 4; rg++) {
      float ls = 0.f;
#pragma unroll
      for (int t = 0; t < 13; t++) {
        const float e = __expf(s[t][rg]);
        s[t][rg] = e;
        ls += e;
      }
      ls += __shfl_xor(ls, 1);
      ls += __shfl_xor(ls, 2);
      ls += __shfl_xor(ls, 4);
      ls += __shfl_xor(ls, 8);
      rinv[rg] = 1.f / ls;
    }
#pragma unroll
    for (int t = 0; t < 13; t++)
#pragma unroll
      for (int rg = 0; rg < 4; rg++)
        Ps[wid][(fj * 4 + rg) * VSTR + t * 16 + fr] = f2b(s[t][rg]);
    __threadfence_block();

    f32x4 o[8] = {};
#pragma unroll
    for (int kc = 0; kc < 7; kc++) {
      const bf16x8 pf = *(const bf16x8*)&Ps[wid][fr * VSTR + kc * 32 + fk];
#pragma unroll
      for (int dt = 0; dt < 8; dt++) {
        const bf16x8 vf = *(const bf16x8*)&Vs[(dt * 16 + fr) * VSTR + kc * 32 + fk];
        o[dt] = __builtin_amdgcn_mfma_f32_16x16x32_bf16(pf, vf, o[dt], 0, 0, 0);
      }
    }
#pragma unroll
    for (int rg = 0; rg < 4; rg++) {
      const int n = rt * 16 + fj * 4 + rg;
      if (n < NQ) {
        const float rv = rinv[rg];
#pragma unroll
        for (int dt = 0; dt < 8; dt++) {
          float x = o[dt][rg] * rv;
          x = x / (1.f + __expf(-x));
          AO[((size_t)(b * NQ + n)) * VAD + h * 128 + dt * 16 + fr] = f2b(x);
        }
      }
    }
    __threadfence_block();
  }
}

// ---------------- host launcher ----------------

extern "C" void kernel_launch(void* const* d_in, const int* in_sizes, int n_in,
                              void* d_out, int out_size, void* d_ws, size_t ws_size,
                              hipStream_t stream) {
  const float* x          = (const float*)d_in[0];
  const float* qkv_w      = (const float*)d_in[1];
  const float* qkv_gamma  = (const float*)d_in[2];
  const float* qkv_beta   = (const float*)d_in[3];
  const float* qkv_mean   = (const float*)d_in[4];
  const float* qkv_var    = (const float*)d_in[5];
  const float* attn_bias  = (const float*)d_in[6];
  const float* proj_w     = (const float*)d_in[7];
  const float* proj_gamma = (const float*)d_in[8];
  const float* proj_beta  = (const float*)d_in[9];
  const float* proj_mean  = (const float*)d_in[10];
  const float* proj_var   = (const float*)d_in[11];

  const size_t szXB    = (size_t)MTOT * DIMX * 2;
  const size_t szQKVW  = (size_t)QKVD * DIMX * 2;
  const size_t szPROJW = (size_t)DIMX * VAD * 2;
  const size_t szQK    = (size_t)128 * NHD * NQ * 32 * 2;
  const size_t szV     = (size_t)128 * NHD * 128 * VTS * 2;
  const size_t szBT    = (size_t)NHD * BTS * BTS * 4;
  const size_t szAO    = (size_t)MTOT * VAD * 2;
  const size_t szX     = (szXB + szQKVW > szAO) ? (szXB + szQKVW) : szAO;

  char* w = (char*)d_ws;
  u16* projwb = (u16*)w; w += szPROJW;
  float* inv1 = (float*)w; w += QKVD * 4;
  float* off1 = (float*)w; w += QKVD * 4;
  float* inv2 = (float*)w; w += DIMX * 4;
  float* off2 = (float*)w; w += DIMX * 4;
  float* biasT = (float*)w; w += szBT;
  u16* Qb = (u16*)w; w += szQK;     // (B,H,N,32), Q pre-scaled
  u16* Kb = (u16*)w; w += szQK;     // (B,H,N,32)
  u16* Vt = (u16*)w; w += szV;      // (B,H,128,VTS) transposed, padded
  char* regionX = w; w += szX;
  u16* xb    = (u16*)regionX;
  u16* qkvwb = (u16*)(regionX + szXB);
  u16* AO    = (u16*)regionX;       // aliases xb/qkvwb (disjoint lifetimes)

  if ((size_t)(w - (char*)d_ws) > ws_size) return;

  cvt_kernel<<<MTOT * DIMX / 4 / 256, 256, 0, stream>>>(x, xb, MTOT * DIMX / 4);
  cvt_wqkv<<<(QKVD * DIMX / 4 + 255) / 256, 256, 0, stream>>>(qkv_w, qkvwb);
  cvt_kernel<<<DIMX * VAD / 4 / 256, 256, 0, stream>>>(proj_w, projwb, DIMX * VAD / 4);
  bn_tab_qkv<<<(QKVD + 255) / 256, 256, 0, stream>>>(qkv_gamma, qkv_beta, qkv_mean, qkv_var, inv1, off1);
  bn_tab<<<(DIMX + 255) / 256, 256, 0, stream>>>(proj_gamma, proj_beta, proj_mean, proj_var, inv2, off2, DIMX);
  bias_expand<<<(NHD * BTS * BTS + 255) / 256, 256, 0, stream>>>(attn_bias, biasT);
  pad_vt<<<(128 * NHD * 128 * 14 + 255) / 256, 256, 0, stream>>>(Vt);

  gemm_bt<0><<<dim3(QKVD / 128, MTOT / 128), 256, 0, stream>>>(
      xb, qkvwb, DIMX, inv1, off1, Qb, Kb, Vt, nullptr);
  attn_kernel<<<128 * NHD, 512, 0, stream>>>(Qb, Kb, Vt, biasT, AO);
  gemm_bt<1><<<dim3(DIMX / 128, MTOT / 128), 256, 0, stream>>>(
      AO, projwb, VAD, inv2, off2, nullptr, nullptr, nullptr, (float*)d_out);
}